// Round 7
// baseline (1971.882 us; speedup 1.0000x reference)
//
#include <hip/hip_runtime.h>
#include <hip/hip_bf16.h>

constexpr int N_NODES = 100000;
constexpr int N_EDGES = 3200000;
constexpr int N_PAIRS = 500000;
constexpr int D       = 256;
constexpr int NOCT    = 8;      // feature octants (64 B each) pinned to XCDs
constexpr int OFEAT   = 32;     // bf16 features per octant

using frag_ab = __attribute__((ext_vector_type(8))) short;
using frag_cd = __attribute__((ext_vector_type(4))) float;
typedef unsigned short ushort8 __attribute__((ext_vector_type(8)));

static __device__ __forceinline__ float b2f(unsigned short u) {
  return __uint_as_float(((unsigned)u) << 16);
}
static __device__ __forceinline__ unsigned short f2bf(float f) {
  unsigned u = __float_as_uint(f);
  unsigned r = (u + 0x7fff + ((u >> 16) & 1)) >> 16;   // RNE
  return (unsigned short)r;
}

// ---------------------------------------------------------------------------
__global__ void zero_ints(int* __restrict__ p, int n) {
  int i = blockIdx.x * blockDim.x + threadIdx.x;
  if (i < n) p[i] = 0;
}

__global__ void copy_ints(const int* __restrict__ in, int* __restrict__ out, int n) {
  int i = blockIdx.x * blockDim.x + threadIdx.x;
  if (i < n) out[i] = in[i];
}

__global__ void f32_to_bf16(const float4* __restrict__ in, ushort4* __restrict__ out, int n4) {
  int i = blockIdx.x * blockDim.x + threadIdx.x;
  int stride = gridDim.x * blockDim.x;
  for (; i < n4; i += stride) {
    const float4 v = in[i];
    ushort4 o;
    o.x = f2bf(v.x); o.y = f2bf(v.y); o.z = f2bf(v.z); o.w = f2bf(v.w);
    out[i] = o;
  }
}

// counts[dst]++
__global__ void hist_kernel(const int* __restrict__ ei, int* __restrict__ counts) {
  int i = blockIdx.x * blockDim.x + threadIdx.x;
  if (i < N_EDGES) atomicAdd(&counts[ei[N_EDGES + i]], 1);
}

// exclusive prefix sum of counts -> cursor (single block, 1024 threads)
__global__ __launch_bounds__(1024) void scan_kernel(const int* __restrict__ counts,
                                                    int* __restrict__ cursor, int n) {
  __shared__ int wsum[16];
  __shared__ int carry;
  const int t = threadIdx.x, lane = t & 63, w = t >> 6;
  if (t == 0) carry = 0;
  __syncthreads();
  for (int base = 0; base < n; base += 1024) {
    int v = (base + t < n) ? counts[base + t] : 0;
    int s = v;
#pragma unroll
    for (int off = 1; off < 64; off <<= 1) {
      int u = __shfl_up(s, off, 64);
      if (lane >= off) s += u;
    }
    if (lane == 63) wsum[w] = s;
    __syncthreads();
    if (t < 16) {
      int ws = wsum[t];
#pragma unroll
      for (int off = 1; off < 16; off <<= 1) {
        int u = __shfl_up(ws, off, 64);
        if (lane >= off) ws += u;
      }
      wsum[t] = ws;
    }
    __syncthreads();
    const int wpre = (w == 0) ? 0 : wsum[w - 1];
    if (base + t < n) cursor[base + t] = carry + wpre + s - v;
    __syncthreads();
    if (t == 0) carry += wsum[15];
    __syncthreads();
  }
}

// XCD-partitioned fill (R4-proven): csr[pos[dst]++] = src
constexpr int FILL_SEG = 4096;
__global__ __launch_bounds__(256) void fill_kernel(const int* __restrict__ ei,
                                                   int* __restrict__ pos,
                                                   int* __restrict__ csr) {
  const int range = blockIdx.x & 7;
  const int seg   = blockIdx.x >> 3;
  const int base  = seg * FILL_SEG;
  const int lo = range * 12500, hi = lo + 12500;
#pragma unroll
  for (int j = 0; j < FILL_SEG / 256; ++j) {
    const int i = base + j * 256 + threadIdx.x;
    if (i < N_EDGES) {
      const int dst = ei[N_EDGES + i];
      if (dst >= lo && dst < hi) {
        const int p = atomicAdd(&pos[dst], 1);
        csr[p] = ei[i];
      }
    }
  }
}

// ---------------------------------------------------------------------------
// Octant gather: wave handles (node, octant). octant = blockIdx&7 -> pinned to
// one XCD (round-robin block->XCD), so each XCD's L2 streams only its own
// 6.4 MB feature slice and row-octant re-reads (~32x) all hit the same L2.
// Lane reads 2 B; half-wave (32 lanes) covers one 64 B row-octant; half-waves
// take alternating edges; 8-deep unroll -> 16 rows in flight per wave.
// ---------------------------------------------------------------------------
__global__ __launch_bounds__(256) void gather_oct(const ushort* __restrict__ x,
                                                  const int* __restrict__ csr,
                                                  const int* __restrict__ cursor,
                                                  const int* __restrict__ counts,
                                                  ushort* __restrict__ out) {
  const int oct  = blockIdx.x & 7;
  const int nb   = blockIdx.x >> 3;          // 0..3124
  const int wid  = threadIdx.x >> 6;
  const int lane = threadIdx.x & 63;
  const int half = lane >> 5;
  const int fl   = lane & 31;
  const int foff = oct * OFEAT + fl;

  for (int node = nb * 4 + wid; node < N_NODES; node += 12500) {
    const int beg = cursor[node];
    const int end = beg + counts[node];

    float acc = (half == 0) ? b2f(x[(size_t)node * D + foff]) : 0.f;

    int e = beg + half;
    for (; e + 14 < end; e += 16) {
      int s0 = csr[e];      int s1 = csr[e + 2];
      int s2 = csr[e + 4];  int s3 = csr[e + 6];
      int s4 = csr[e + 8];  int s5 = csr[e + 10];
      int s6 = csr[e + 12]; int s7 = csr[e + 14];
      float a0 = b2f(x[(size_t)s0 * D + foff]);
      float a1 = b2f(x[(size_t)s1 * D + foff]);
      float a2 = b2f(x[(size_t)s2 * D + foff]);
      float a3 = b2f(x[(size_t)s3 * D + foff]);
      float a4 = b2f(x[(size_t)s4 * D + foff]);
      float a5 = b2f(x[(size_t)s5 * D + foff]);
      float a6 = b2f(x[(size_t)s6 * D + foff]);
      float a7 = b2f(x[(size_t)s7 * D + foff]);
      acc += ((a0 + a1) + (a2 + a3)) + ((a4 + a5) + (a6 + a7));
    }
    for (; e < end; e += 2)
      acc += b2f(x[(size_t)csr[e] * D + foff]);

    acc += __shfl_xor(acc, 32, 64);
    if (half == 0) out[(size_t)node * D + foff] = f2bf(acc);
  }
}

// ---------------------------------------------------------------------------
// C[r][c] = relu( sum_k A[r][k]*W[c][k] + bias[c] ), bf16 in / bf16 out.
// 4 waves, 64x64 tile, K=256 staged in LDS with XOR swizzle. (unchanged)
// ---------------------------------------------------------------------------
__global__ __launch_bounds__(256) void gemm_mfma_bf16(const ushort* __restrict__ A,
                                                      const ushort* __restrict__ W,
                                                      const float* __restrict__ bias,
                                                      ushort* __restrict__ C,
                                                      int M) {
  __shared__ __align__(16) ushort As[64 * 256];
  __shared__ __align__(16) ushort Ws[64 * 256];

  const int t = threadIdx.x;
  const int w = t >> 6, l = t & 63;
  const int row0 = blockIdx.x * 64;
  const int col0 = blockIdx.y * 64;

  {
    const float4 zero4 = {0.f, 0.f, 0.f, 0.f};
#pragma unroll
    for (int i = 0; i < 8; ++i) {
      const int chunk = t + i * 256;
      const int r  = chunk >> 5;
      const int kb = (chunk & 31) << 4;
      const int swz = kb ^ ((r & 7) << 4);
      const int grow = row0 + r;
      float4 av = zero4;
      if (grow < M)
        av = *reinterpret_cast<const float4*>(
            reinterpret_cast<const char*>(A) + (size_t)grow * 512 + kb);
      *reinterpret_cast<float4*>(reinterpret_cast<char*>(As) + r * 512 + swz) = av;
      const float4 wv = *reinterpret_cast<const float4*>(
          reinterpret_cast<const char*>(W) + (size_t)(col0 + r) * 512 + kb);
      *reinterpret_cast<float4*>(reinterpret_cast<char*>(Ws) + r * 512 + swz) = wv;
    }
  }
  __syncthreads();

  const int g  = l >> 4;
  const int fr = l & 15;

  frag_cd acc[4];
#pragma unroll
  for (int c = 0; c < 4; ++c) {
    acc[c][0] = 0.f; acc[c][1] = 0.f; acc[c][2] = 0.f; acc[c][3] = 0.f;
  }

  const int arow = w * 16 + fr;
  const char* Asb = reinterpret_cast<const char*>(As);
  const char* Wsb = reinterpret_cast<const char*>(Ws);
#pragma unroll
  for (int ks = 0; ks < 8; ++ks) {
    const int kb = ks * 64 + g * 16;
    const frag_ab af = *reinterpret_cast<const frag_ab*>(
        Asb + arow * 512 + (kb ^ ((arow & 7) << 4)));
#pragma unroll
    for (int c = 0; c < 4; ++c) {
      const int wrow = c * 16 + fr;
      const frag_ab bf = *reinterpret_cast<const frag_ab*>(
          Wsb + wrow * 512 + (kb ^ ((wrow & 7) << 4)));
      acc[c] = __builtin_amdgcn_mfma_f32_16x16x32_bf16(af, bf, acc[c], 0, 0, 0);
    }
  }
  __syncthreads();

  ushort* Ct = As;
#pragma unroll
  for (int c = 0; c < 4; ++c) {
    const int col = c * 16 + fr;
    const float bv = bias[col0 + col];
#pragma unroll
    for (int r = 0; r < 4; ++r) {
      const int rl = w * 16 + g * 4 + r;
      Ct[rl * 64 + col] = f2bf(fmaxf(acc[c][r] + bv, 0.f));
    }
  }
  __syncthreads();
#pragma unroll
  for (int i = 0; i < 2; ++i) {
    const int chunk = t + i * 256;
    const int r  = chunk >> 3;
    const int cb = (chunk & 7) << 4;
    const int grow = row0 + r;
    if (grow < M)
      *reinterpret_cast<float4*>(reinterpret_cast<char*>(C) + (size_t)grow * 512 + col0 * 2 + cb) =
          *reinterpret_cast<const float4*>(reinterpret_cast<const char*>(Ct) + r * 128 + cb);
  }
}

// ---------------------------------------------------------------------------
// Pair head, octant-partitioned. Wave = (pair, oct); half-wave reads one 64 B
// slice of h[idx[2p+half]]; full-wave reduce -> partial logits for this oct.
// partial layout: [pair][oct][2] f32 (written once each, no init needed).
// ---------------------------------------------------------------------------
__global__ __launch_bounds__(256) void pair_partial(const ushort* __restrict__ h,
                                                    const int* __restrict__ idx,
                                                    const float* __restrict__ W3,
                                                    float* __restrict__ partial) {
  const int oct  = blockIdx.x & 7;
  const int pb   = blockIdx.x >> 3;          // 0..3124
  const int wid  = threadIdx.x >> 6;
  const int lane = threadIdx.x & 63;
  const int half = lane >> 5;
  const int fl   = lane & 31;
  const int wi   = half * 256 + oct * OFEAT + fl;
  const float w0 = W3[wi];
  const float w1 = W3[512 + wi];
  const int foff = oct * OFEAT + fl;

  for (int pair = pb * 4 + wid; pair < N_PAIRS; pair += 12500) {
    const int ia = idx[2 * pair + half];
    const float a = b2f(h[(size_t)ia * D + foff]);
    float l0 = a * w0;
    float l1 = a * w1;
#pragma unroll
    for (int off = 32; off > 0; off >>= 1) {
      l0 += __shfl_down(l0, off, 64);
      l1 += __shfl_down(l1, off, 64);
    }
    if (lane == 0) {
      partial[(size_t)pair * 16 + oct * 2]     = l0;
      partial[(size_t)pair * 16 + oct * 2 + 1] = l1;
    }
  }
}

__global__ __launch_bounds__(256) void pair_finish(const float* __restrict__ partial,
                                                   const float* __restrict__ b3,
                                                   float* __restrict__ out) {
  const int pair = blockIdx.x * blockDim.x + threadIdx.x;
  if (pair >= N_PAIRS) return;
  const float4* p = reinterpret_cast<const float4*>(partial + (size_t)pair * 16);
  float l0 = b3[0], l1 = b3[1];
#pragma unroll
  for (int k = 0; k < 4; ++k) {
    const float4 v = p[k];
    l0 += v.x + v.z;
    l1 += v.y + v.w;
  }
  const float m = fmaxf(l0, l1);
  const float lse = m + logf(expf(l0 - m) + expf(l1 - m));
  out[2 * (size_t)pair + 0] = l0 - lse;
  out[2 * (size_t)pair + 1] = l1 - lse;
}

// ---------------------------------------------------------------------------
extern "C" void kernel_launch(void* const* d_in, const int* in_sizes, int n_in,
                              void* d_out, int out_size, void* d_ws, size_t ws_size,
                              hipStream_t stream) {
  const float* x   = (const float*)d_in[0];
  const int*   ei  = (const int*)d_in[1];
  const int*   idx = (const int*)d_in[2];
  const float* W1  = (const float*)d_in[3];
  const float* b1  = (const float*)d_in[4];
  const float* W2  = (const float*)d_in[5];
  const float* b2  = (const float*)d_in[6];
  const float* W3  = (const float*)d_in[7];
  const float* b3  = (const float*)d_in[8];
  float* out = (float*)d_out;

  char* ws = (char*)d_ws;
  ushort* xb    = (ushort*)(ws);                   // 51.2 MB
  ushort* aggb  = (ushort*)(ws + 51200000);        // 51.2 MB
  float*  partial = (float*)(ws + 51200000);       // 32 MB, aliases aggb (dead after gemm2)
  ushort* hb    = (ushort*)(ws + 102400000);       // 51.2 MB
  ushort* W1b   = (ushort*)(ws + 153600000);
  ushort* W2b   = (ushort*)(ws + 153731072);
  int* counts   = (int*)(ws + 153862144);          // 400 KB
  int* cursor   = (int*)(ws + 154262144);          // 400 KB
  int* pos      = (int*)(ws + 154662144);          // 400 KB
  int* csr      = (int*)(ws + 155062144);          // 12.8 MB

  const dim3 blk(256);
  const size_t feat = (size_t)N_NODES * D;
  const dim3 zeroGrid((N_NODES + 255) / 256);
  const dim3 edgeGrid((N_EDGES + 255) / 256);
  const int  nseg = (N_EDGES + FILL_SEG - 1) / FILL_SEG;
  const dim3 fillGrid(8 * nseg);
  const dim3 octGrid(8 * 3125);                    // 25000 blocks, oct = bid&7
  const dim3 gemmGrid((N_NODES + 63) / 64, D / 64);
  const dim3 pairGrid(8 * 3125);
  const dim3 finGrid((N_PAIRS + 255) / 256);

  // ---- converts ----
  f32_to_bf16<<<dim3(4096), blk, 0, stream>>>((const float4*)x, (ushort4*)xb, (int)(feat / 4));
  f32_to_bf16<<<dim3(64), blk, 0, stream>>>((const float4*)W1, (ushort4*)W1b, 65536 / 4);
  f32_to_bf16<<<dim3(64), blk, 0, stream>>>((const float4*)W2, (ushort4*)W2b, 65536 / 4);

  // ---- CSR build (simple dst-CSR) ----
  zero_ints<<<zeroGrid, blk, 0, stream>>>(counts, N_NODES);
  hist_kernel<<<edgeGrid, blk, 0, stream>>>(ei, counts);
  scan_kernel<<<1, 1024, 0, stream>>>(counts, cursor, N_NODES);
  copy_ints<<<zeroGrid, blk, 0, stream>>>(cursor, pos, N_NODES);
  fill_kernel<<<fillGrid, blk, 0, stream>>>(ei, pos, csr);

  // ---- layer 1 ----
  gather_oct<<<octGrid, blk, 0, stream>>>(xb, csr, cursor, counts, aggb);
  gemm_mfma_bf16<<<gemmGrid, blk, 0, stream>>>(aggb, W1b, b1, hb, N_NODES);

  // ---- layer 2 ----
  gather_oct<<<octGrid, blk, 0, stream>>>(hb, csr, cursor, counts, aggb);
  gemm_mfma_bf16<<<gemmGrid, blk, 0, stream>>>(aggb, W2b, b2, hb, N_NODES);

  // ---- pair head (octant partials into aliased aggb, then finish) ----
  pair_partial<<<pairGrid, blk, 0, stream>>>(hb, idx, W3, partial);
  pair_finish<<<finGrid, blk, 0, stream>>>(partial, b3, out);
}

// Round 8
// 990.762 us; speedup vs baseline: 1.9903x; 1.9903x over previous
//
#include <hip/hip_runtime.h>
#include <hip/hip_bf16.h>

constexpr int N_NODES = 100000;
constexpr int N_EDGES = 3200000;
constexpr int N_PAIRS = 500000;
constexpr int D       = 256;

using frag_ab = __attribute__((ext_vector_type(8))) short;
using frag_cd = __attribute__((ext_vector_type(4))) float;
typedef unsigned short ushort8 __attribute__((ext_vector_type(8)));

static __device__ __forceinline__ float b2f(unsigned short u) {
  return __uint_as_float(((unsigned)u) << 16);
}
static __device__ __forceinline__ unsigned short f2bf(float f) {
  unsigned u = __float_as_uint(f);
  unsigned r = (u + 0x7fff + ((u >> 16) & 1)) >> 16;   // RNE
  return (unsigned short)r;
}

// ---------------------------------------------------------------------------
__global__ void zero_ints(int* __restrict__ p, int n) {
  int i = blockIdx.x * blockDim.x + threadIdx.x;
  if (i < n) p[i] = 0;
}

__global__ void copy_ints(const int* __restrict__ in, int* __restrict__ out, int n) {
  int i = blockIdx.x * blockDim.x + threadIdx.x;
  if (i < n) out[i] = in[i];
}

__global__ void f32_to_bf16(const float4* __restrict__ in, ushort4* __restrict__ out, int n4) {
  int i = blockIdx.x * blockDim.x + threadIdx.x;
  int stride = gridDim.x * blockDim.x;
  for (; i < n4; i += stride) {
    const float4 v = in[i];
    ushort4 o;
    o.x = f2bf(v.x); o.y = f2bf(v.y); o.z = f2bf(v.z); o.w = f2bf(v.w);
    out[i] = o;
  }
}

// counts[dst]++
__global__ void hist_kernel(const int* __restrict__ ei, int* __restrict__ counts) {
  int i = blockIdx.x * blockDim.x + threadIdx.x;
  if (i < N_EDGES) atomicAdd(&counts[ei[N_EDGES + i]], 1);
}

// exclusive prefix sum of counts -> cursor (single block, 1024 threads)
__global__ __launch_bounds__(1024) void scan_kernel(const int* __restrict__ counts,
                                                    int* __restrict__ cursor, int n) {
  __shared__ int wsum[16];
  __shared__ int carry;
  const int t = threadIdx.x, lane = t & 63, w = t >> 6;
  if (t == 0) carry = 0;
  __syncthreads();
  for (int base = 0; base < n; base += 1024) {
    int v = (base + t < n) ? counts[base + t] : 0;
    int s = v;
#pragma unroll
    for (int off = 1; off < 64; off <<= 1) {
      int u = __shfl_up(s, off, 64);
      if (lane >= off) s += u;
    }
    if (lane == 63) wsum[w] = s;
    __syncthreads();
    if (t < 16) {
      int ws = wsum[t];
#pragma unroll
      for (int off = 1; off < 16; off <<= 1) {
        int u = __shfl_up(ws, off, 64);
        if (lane >= off) ws += u;
      }
      wsum[t] = ws;
    }
    __syncthreads();
    const int wpre = (w == 0) ? 0 : wsum[w - 1];
    if (base + t < n) cursor[base + t] = carry + wpre + s - v;
    __syncthreads();
    if (t == 0) carry += wsum[15];
    __syncthreads();
  }
}

// XCD-partitioned fill: csr[pos[dst]++] = src  (writes stay L2-local per range)
constexpr int FILL_SEG = 4096;
__global__ __launch_bounds__(256) void fill_kernel(const int* __restrict__ ei,
                                                   int* __restrict__ pos,
                                                   int* __restrict__ csr) {
  const int range = blockIdx.x & 7;
  const int seg   = blockIdx.x >> 3;
  const int base  = seg * FILL_SEG;
  const int lo = range * 12500, hi = lo + 12500;
#pragma unroll
  for (int j = 0; j < FILL_SEG / 256; ++j) {
    const int i = base + j * 256 + threadIdx.x;
    if (i < N_EDGES) {
      const int dst = ei[N_EDGES + i];
      if (dst >= lo && dst < hi) {
        const int p = atomicAdd(&pos[dst], 1);
        csr[p] = ei[i];
      }
    }
  }
}

// out[node] = x[node] + sum_{s in csr} x[s]; bf16 rows, f32 accumulate.
// One wave per node; half-waves take alternating edges; lane reads 16 B.
__global__ __launch_bounds__(256) void gather_agg_bf16(const ushort* __restrict__ x,
                                                       const int* __restrict__ csr,
                                                       const int* __restrict__ cursor,
                                                       const int* __restrict__ counts,
                                                       ushort* __restrict__ out) {
  const int node = blockIdx.x * 4 + (threadIdx.x >> 6);
  const int lane = threadIdx.x & 63;
  const int half = lane >> 5;
  const int fl   = lane & 31;
  if (node >= N_NODES) return;
  const int beg = cursor[node];
  const int end = beg + counts[node];
  const size_t fo = (size_t)fl * 8;

  float acc[8];
#pragma unroll
  for (int j = 0; j < 8; ++j) acc[j] = 0.f;

  if (half == 0) {
    const ushort8 self = *reinterpret_cast<const ushort8*>(x + (size_t)node * D + fo);
#pragma unroll
    for (int j = 0; j < 8; ++j) acc[j] += b2f(self[j]);
  }

  int o = beg + half;
  for (; o + 6 < end; o += 8) {
    const int s0 = csr[o], s1 = csr[o + 2], s2 = csr[o + 4], s3 = csr[o + 6];
    const ushort8 v0 = *reinterpret_cast<const ushort8*>(x + (size_t)s0 * D + fo);
    const ushort8 v1 = *reinterpret_cast<const ushort8*>(x + (size_t)s1 * D + fo);
    const ushort8 v2 = *reinterpret_cast<const ushort8*>(x + (size_t)s2 * D + fo);
    const ushort8 v3 = *reinterpret_cast<const ushort8*>(x + (size_t)s3 * D + fo);
#pragma unroll
    for (int j = 0; j < 8; ++j)
      acc[j] += (b2f(v0[j]) + b2f(v1[j])) + (b2f(v2[j]) + b2f(v3[j]));
  }
  for (; o < end; o += 2) {
    const ushort8 v = *reinterpret_cast<const ushort8*>(x + (size_t)csr[o] * D + fo);
#pragma unroll
    for (int j = 0; j < 8; ++j) acc[j] += b2f(v[j]);
  }

#pragma unroll
  for (int j = 0; j < 8; ++j) acc[j] += __shfl_xor(acc[j], 32, 64);

  if (half == 0) {
    ushort8 ov;
#pragma unroll
    for (int j = 0; j < 8; ++j) ov[j] = f2bf(acc[j]);
    *reinterpret_cast<ushort8*>(out + (size_t)node * D + fo) = ov;
  }
}

// ---------------------------------------------------------------------------
// C[r][c] = relu( sum_k A[r][k]*W[c][k] + bias[c] ), bf16 in / bf16 out.
// 4 waves, 64x64 tile, K=256 staged in LDS with XOR swizzle.
// ---------------------------------------------------------------------------
__global__ __launch_bounds__(256) void gemm_mfma_bf16(const ushort* __restrict__ A,
                                                      const ushort* __restrict__ W,
                                                      const float* __restrict__ bias,
                                                      ushort* __restrict__ C,
                                                      int M) {
  __shared__ __align__(16) ushort As[64 * 256];
  __shared__ __align__(16) ushort Ws[64 * 256];

  const int t = threadIdx.x;
  const int w = t >> 6, l = t & 63;
  const int row0 = blockIdx.x * 64;
  const int col0 = blockIdx.y * 64;

  {
    const float4 zero4 = {0.f, 0.f, 0.f, 0.f};
#pragma unroll
    for (int i = 0; i < 8; ++i) {
      const int chunk = t + i * 256;
      const int r  = chunk >> 5;
      const int kb = (chunk & 31) << 4;
      const int swz = kb ^ ((r & 7) << 4);
      const int grow = row0 + r;
      float4 av = zero4;
      if (grow < M)
        av = *reinterpret_cast<const float4*>(
            reinterpret_cast<const char*>(A) + (size_t)grow * 512 + kb);
      *reinterpret_cast<float4*>(reinterpret_cast<char*>(As) + r * 512 + swz) = av;
      const float4 wv = *reinterpret_cast<const float4*>(
          reinterpret_cast<const char*>(W) + (size_t)(col0 + r) * 512 + kb);
      *reinterpret_cast<float4*>(reinterpret_cast<char*>(Ws) + r * 512 + swz) = wv;
    }
  }
  __syncthreads();

  const int g  = l >> 4;
  const int fr = l & 15;

  frag_cd acc[4];
#pragma unroll
  for (int c = 0; c < 4; ++c) {
    acc[c][0] = 0.f; acc[c][1] = 0.f; acc[c][2] = 0.f; acc[c][3] = 0.f;
  }

  const int arow = w * 16 + fr;
  const char* Asb = reinterpret_cast<const char*>(As);
  const char* Wsb = reinterpret_cast<const char*>(Ws);
#pragma unroll
  for (int ks = 0; ks < 8; ++ks) {
    const int kb = ks * 64 + g * 16;
    const frag_ab af = *reinterpret_cast<const frag_ab*>(
        Asb + arow * 512 + (kb ^ ((arow & 7) << 4)));
#pragma unroll
    for (int c = 0; c < 4; ++c) {
      const int wrow = c * 16 + fr;
      const frag_ab bf = *reinterpret_cast<const frag_ab*>(
          Wsb + wrow * 512 + (kb ^ ((wrow & 7) << 4)));
      acc[c] = __builtin_amdgcn_mfma_f32_16x16x32_bf16(af, bf, acc[c], 0, 0, 0);
    }
  }
  __syncthreads();

  ushort* Ct = As;
#pragma unroll
  for (int c = 0; c < 4; ++c) {
    const int col = c * 16 + fr;
    const float bv = bias[col0 + col];
#pragma unroll
    for (int r = 0; r < 4; ++r) {
      const int rl = w * 16 + g * 4 + r;
      Ct[rl * 64 + col] = f2bf(fmaxf(acc[c][r] + bv, 0.f));
    }
  }
  __syncthreads();
#pragma unroll
  for (int i = 0; i < 2; ++i) {
    const int chunk = t + i * 256;
    const int r  = chunk >> 3;
    const int cb = (chunk & 7) << 4;
    const int grow = row0 + r;
    if (grow < M)
      *reinterpret_cast<float4*>(reinterpret_cast<char*>(C) + (size_t)grow * 512 + col0 * 2 + cb) =
          *reinterpret_cast<const float4*>(reinterpret_cast<const char*>(Ct) + r * 128 + cb);
  }
}

// ---------------------------------------------------------------------------
// Per-node head projection: proj[n] = (a0, a1, b0, b1) where
//   a_r = h[n] . W3[r][0:256]   (first-half weights)
//   b_r = h[n] . W3[r][256:512] (second-half weights)
// One wave per node, 4 nodes per block.
// ---------------------------------------------------------------------------
__global__ __launch_bounds__(256) void proj_kernel(const ushort* __restrict__ h,
                                                   const float* __restrict__ W3,
                                                   float4* __restrict__ proj) {
  const int node = blockIdx.x * 4 + (threadIdx.x >> 6);
  const int lane = threadIdx.x & 63;
  if (node >= N_NODES) return;

  const ushort4 hv = *reinterpret_cast<const ushort4*>(h + (size_t)node * D + lane * 4);
  const float h0 = b2f(hv.x), h1 = b2f(hv.y), h2 = b2f(hv.z), h3 = b2f(hv.w);

  const float4 wa0 = *reinterpret_cast<const float4*>(W3 + lane * 4);          // row0 k<256
  const float4 wa1 = *reinterpret_cast<const float4*>(W3 + 512 + lane * 4);    // row1 k<256
  const float4 wb0 = *reinterpret_cast<const float4*>(W3 + 256 + lane * 4);    // row0 k>=256
  const float4 wb1 = *reinterpret_cast<const float4*>(W3 + 768 + lane * 4);    // row1 k>=256

  float a0 = h0 * wa0.x + h1 * wa0.y + h2 * wa0.z + h3 * wa0.w;
  float a1 = h0 * wa1.x + h1 * wa1.y + h2 * wa1.z + h3 * wa1.w;
  float b0 = h0 * wb0.x + h1 * wb0.y + h2 * wb0.z + h3 * wb0.w;
  float b1 = h0 * wb1.x + h1 * wb1.y + h2 * wb1.z + h3 * wb1.w;

#pragma unroll
  for (int off = 32; off > 0; off >>= 1) {
    a0 += __shfl_xor(a0, off, 64);
    a1 += __shfl_xor(a1, off, 64);
    b0 += __shfl_xor(b0, off, 64);
    b1 += __shfl_xor(b1, off, 64);
  }
  if (lane == 0) {
    float4 o; o.x = a0; o.y = a1; o.z = b0; o.w = b1;
    proj[node] = o;
  }
}

// logits(p) = (proj[i0].x + proj[i1].z + b3[0], proj[i0].y + proj[i1].w + b3[1])
__global__ __launch_bounds__(256) void pair_lite(const float4* __restrict__ proj,
                                                 const int* __restrict__ idx,
                                                 const float* __restrict__ b3,
                                                 float* __restrict__ out) {
  const int p = blockIdx.x * blockDim.x + threadIdx.x;
  if (p >= N_PAIRS) return;
  const int2 ii = reinterpret_cast<const int2*>(idx)[p];
  const float4 pa = proj[ii.x];
  const float4 pb = proj[ii.y];
  float l0 = pa.x + pb.z + b3[0];
  float l1 = pa.y + pb.w + b3[1];
  const float m = fmaxf(l0, l1);
  const float lse = m + logf(expf(l0 - m) + expf(l1 - m));
  float2 o; o.x = l0 - lse; o.y = l1 - lse;
  reinterpret_cast<float2*>(out)[p] = o;
}

// ---------------------------------------------------------------------------
extern "C" void kernel_launch(void* const* d_in, const int* in_sizes, int n_in,
                              void* d_out, int out_size, void* d_ws, size_t ws_size,
                              hipStream_t stream) {
  const float* x   = (const float*)d_in[0];
  const int*   ei  = (const int*)d_in[1];
  const int*   idx = (const int*)d_in[2];
  const float* W1  = (const float*)d_in[3];
  const float* b1  = (const float*)d_in[4];
  const float* W2  = (const float*)d_in[5];
  const float* b2  = (const float*)d_in[6];
  const float* W3  = (const float*)d_in[7];
  const float* b3  = (const float*)d_in[8];
  float* out = (float*)d_out;

  char* ws = (char*)d_ws;
  ushort* xb    = (ushort*)(ws);                   // 51.2 MB
  ushort* aggb  = (ushort*)(ws + 51200000);        // 51.2 MB
  ushort* hb    = (ushort*)(ws + 102400000);       // 51.2 MB
  ushort* W1b   = (ushort*)(ws + 153600000);       // 128 KB
  ushort* W2b   = (ushort*)(ws + 153731072);       // 128 KB
  int* counts   = (int*)(ws + 153862144);          // 400 KB
  int* cursor   = (int*)(ws + 154262144);          // 400 KB
  int* pos      = (int*)(ws + 154662144);          // 400 KB
  int* csr      = (int*)(ws + 155062144);          // 12.8 MB
  float4* proj  = (float4*)(ws + 167862144);       // 1.6 MB

  const dim3 blk(256);
  const size_t feat = (size_t)N_NODES * D;
  const dim3 zeroGrid((N_NODES + 255) / 256);
  const dim3 edgeGrid((N_EDGES + 255) / 256);
  const int  nseg = (N_EDGES + FILL_SEG - 1) / FILL_SEG;
  const dim3 fillGrid(8 * nseg);
  const dim3 nodeGrid((N_NODES + 3) / 4);
  const dim3 gemmGrid((N_NODES + 63) / 64, D / 64);
  const dim3 pairGrid((N_PAIRS + 255) / 256);

  // ---- converts ----
  f32_to_bf16<<<dim3(4096), blk, 0, stream>>>((const float4*)x, (ushort4*)xb, (int)(feat / 4));
  f32_to_bf16<<<dim3(64), blk, 0, stream>>>((const float4*)W1, (ushort4*)W1b, 65536 / 4);
  f32_to_bf16<<<dim3(64), blk, 0, stream>>>((const float4*)W2, (ushort4*)W2b, 65536 / 4);

  // ---- CSR build ----
  zero_ints<<<zeroGrid, blk, 0, stream>>>(counts, N_NODES);
  hist_kernel<<<edgeGrid, blk, 0, stream>>>(ei, counts);
  scan_kernel<<<1, 1024, 0, stream>>>(counts, cursor, N_NODES);
  copy_ints<<<zeroGrid, blk, 0, stream>>>(cursor, pos, N_NODES);
  fill_kernel<<<fillGrid, blk, 0, stream>>>(ei, pos, csr);

  // ---- layer 1 ----
  gather_agg_bf16<<<nodeGrid, blk, 0, stream>>>(xb, csr, cursor, counts, aggb);
  gemm_mfma_bf16<<<gemmGrid, blk, 0, stream>>>(aggb, W1b, b1, hb, N_NODES);

  // ---- layer 2 ----
  gather_agg_bf16<<<nodeGrid, blk, 0, stream>>>(hb, csr, cursor, counts, aggb);
  gemm_mfma_bf16<<<gemmGrid, blk, 0, stream>>>(aggb, W2b, b2, hb, N_NODES);

  // ---- pair head: per-node projection, then 16 B-per-pair combine ----
  proj_kernel<<<nodeGrid, blk, 0, stream>>>(hb, W3, proj);
  pair_lite<<<pairGrid, blk, 0, stream>>>(proj, idx, b3, out);
}

// Round 9
// 915.890 us; speedup vs baseline: 2.1530x; 1.0817x over previous
//
#include <hip/hip_runtime.h>
#include <hip/hip_bf16.h>

constexpr int N_NODES = 100000;
constexpr int N_EDGES = 3200000;
constexpr int N_PAIRS = 500000;
constexpr int D       = 256;
constexpr int NRANGE  = 8;
constexpr int RSPAN   = 12500;            // nodes per dst-range
constexpr int SCANN   = 100352;           // 98*1024, padded node count

using frag_ab = __attribute__((ext_vector_type(8))) short;
using frag_cd = __attribute__((ext_vector_type(4))) float;
typedef unsigned short ushort8 __attribute__((ext_vector_type(8)));

static __device__ __forceinline__ float b2f(unsigned short u) {
  return __uint_as_float(((unsigned)u) << 16);
}
static __device__ __forceinline__ unsigned short f2bf(float f) {
  unsigned u = __float_as_uint(f);
  unsigned r = (u + 0x7fff + ((u >> 16) & 1)) >> 16;   // RNE
  return (unsigned short)r;
}

// ---------------------------------------------------------------------------
__global__ void zero_ints(int* __restrict__ p, int n) {
  int i = blockIdx.x * blockDim.x + threadIdx.x;
  if (i < n) p[i] = 0;
}

__global__ void f32_to_bf16(const float4* __restrict__ in, ushort4* __restrict__ out, int n4) {
  int i = blockIdx.x * blockDim.x + threadIdx.x;
  int stride = gridDim.x * blockDim.x;
  for (; i < n4; i += stride) {
    const float4 v = in[i];
    ushort4 o;
    o.x = f2bf(v.x); o.y = f2bf(v.y); o.z = f2bf(v.z); o.w = f2bf(v.w);
    out[i] = o;
  }
}

// both weight matrices in one launch (each 16384 float4)
__global__ void conv_weights(const float4* __restrict__ W1, const float4* __restrict__ W2,
                             ushort4* __restrict__ W1b, ushort4* __restrict__ W2b) {
  const int i = blockIdx.x * blockDim.x + threadIdx.x;
  const bool second = i >= 16384;
  const int k = second ? i - 16384 : i;
  if (k < 16384) {
    const float4 v = second ? W2[k] : W1[k];
    ushort4 o;
    o.x = f2bf(v.x); o.y = f2bf(v.y); o.z = f2bf(v.z); o.w = f2bf(v.w);
    if (second) W2b[k] = o; else W1b[k] = o;
  }
}

// counts[dst]++
__global__ void hist_kernel(const int* __restrict__ ei, int* __restrict__ counts) {
  int i = blockIdx.x * blockDim.x + threadIdx.x;
  if (i < N_EDGES) atomicAdd(&counts[ei[N_EDGES + i]], 1);
}

// --- hierarchical exclusive scan over SCANN ints ----------------------------
__global__ __launch_bounds__(1024) void scan_block_k(const int* __restrict__ in,
                                                     int* __restrict__ out,
                                                     int* __restrict__ bsum) {
  __shared__ int wsum[16];
  const int t = threadIdx.x, lane = t & 63, w = t >> 6;
  const int gid = blockIdx.x * 1024 + t;
  const int v = in[gid];
  int s = v;
#pragma unroll
  for (int off = 1; off < 64; off <<= 1) {
    int u = __shfl_up(s, off, 64);
    if (lane >= off) s += u;
  }
  if (lane == 63) wsum[w] = s;
  __syncthreads();
  if (t < 16) {
    int ws = wsum[t];
#pragma unroll
    for (int off = 1; off < 16; off <<= 1) {
      int u = __shfl_up(ws, off, 64);
      if (lane >= off) ws += u;
    }
    wsum[t] = ws;
  }
  __syncthreads();
  const int wpre = (w == 0) ? 0 : wsum[w - 1];
  out[gid] = wpre + s - v;               // block-local exclusive
  if (t == 1023) bsum[blockIdx.x] = wsum[15];
}

// generic small exclusive scan (n <= 1024): one iteration path of old kernel
__global__ __launch_bounds__(1024) void scan_small(const int* __restrict__ in,
                                                   int* __restrict__ out, int n) {
  __shared__ int wsum[16];
  const int t = threadIdx.x, lane = t & 63, w = t >> 6;
  int v = (t < n) ? in[t] : 0;
  int s = v;
#pragma unroll
  for (int off = 1; off < 64; off <<= 1) {
    int u = __shfl_up(s, off, 64);
    if (lane >= off) s += u;
  }
  if (lane == 63) wsum[w] = s;
  __syncthreads();
  if (t < 16) {
    int ws = wsum[t];
#pragma unroll
    for (int off = 1; off < 16; off <<= 1) {
      int u = __shfl_up(ws, off, 64);
      if (lane >= off) ws += u;
    }
    wsum[t] = ws;
  }
  __syncthreads();
  const int wpre = (w == 0) ? 0 : wsum[w - 1];
  if (t < n) out[t] = wpre + s - v;
}

// add block offsets; also write pos copy and the 8 range partition cursors
__global__ __launch_bounds__(1024) void scan_add_k(int* __restrict__ cursor,
                                                   int* __restrict__ pos,
                                                   const int* __restrict__ bsum2,
                                                   int* __restrict__ rc) {
  const int gid = blockIdx.x * 1024 + threadIdx.x;
  const int v = cursor[gid] + bsum2[gid >> 10];
  cursor[gid] = v;
  pos[gid] = v;
  if (gid < N_NODES && gid % RSPAN == 0) rc[gid / RSPAN] = v;
}

// --- phase A: partition edges into 8 dst-range buckets (one pass) -----------
constexpr int PART_SEG = 4096;
__global__ __launch_bounds__(256) void partition_kernel(const int* __restrict__ ei,
                                                        int* __restrict__ rc,
                                                        int2* __restrict__ bucket) {
  __shared__ int lcnt[NRANGE];
  __shared__ int lbase[NRANGE];
  const int t = threadIdx.x;
  const int base = blockIdx.x * PART_SEG;
  if (t < NRANGE) lcnt[t] = 0;
  __syncthreads();

  int rnk[16], rng[16], sv[16], dv[16];
#pragma unroll
  for (int j = 0; j < 16; ++j) {
    const int i = base + j * 256 + t;
    if (i < N_EDGES) {
      sv[j] = ei[i];
      dv[j] = ei[N_EDGES + i];
      rng[j] = dv[j] / RSPAN;
      rnk[j] = atomicAdd(&lcnt[rng[j]], 1);
    } else rng[j] = -1;
  }
  __syncthreads();
  if (t < NRANGE) lbase[t] = atomicAdd(&rc[t], lcnt[t]);
  __syncthreads();
#pragma unroll
  for (int j = 0; j < 16; ++j) {
    if (rng[j] >= 0) {
      int2 e; e.x = sv[j]; e.y = dv[j];
      bucket[lbase[rng[j]] + rnk[j]] = e;
    }
  }
}

// --- phase B: per-range local fill (reads only own bucket slice) ------------
constexpr int FLB = 128;   // blocks per range
__global__ __launch_bounds__(256) void fill_local(const int2* __restrict__ bucket,
                                                  const int* __restrict__ cursor,
                                                  int* __restrict__ pos,
                                                  int* __restrict__ csr) {
  const int r = blockIdx.x & 7;
  const int j = blockIdx.x >> 3;
  const int beg = cursor[(size_t)r * RSPAN];
  const int end = (r < 7) ? cursor[(size_t)(r + 1) * RSPAN] : N_EDGES;
  for (int i = beg + j * 256 + threadIdx.x; i < end; i += FLB * 256) {
    const int2 e = bucket[i];
    const int p = atomicAdd(&pos[e.y], 1);
    csr[p] = e.x;
  }
}

// out[node] = x[node] + sum_{s in csr} x[s]; bf16 rows, f32 accumulate.
__global__ __launch_bounds__(256) void gather_agg_bf16(const ushort* __restrict__ x,
                                                       const int* __restrict__ csr,
                                                       const int* __restrict__ cursor,
                                                       const int* __restrict__ counts,
                                                       ushort* __restrict__ out) {
  const int node = blockIdx.x * 4 + (threadIdx.x >> 6);
  const int lane = threadIdx.x & 63;
  const int half = lane >> 5;
  const int fl   = lane & 31;
  if (node >= N_NODES) return;
  const int beg = cursor[node];
  const int end = beg + counts[node];
  const size_t fo = (size_t)fl * 8;

  float acc[8];
#pragma unroll
  for (int j = 0; j < 8; ++j) acc[j] = 0.f;

  if (half == 0) {
    const ushort8 self = *reinterpret_cast<const ushort8*>(x + (size_t)node * D + fo);
#pragma unroll
    for (int j = 0; j < 8; ++j) acc[j] += b2f(self[j]);
  }

  int o = beg + half;
  for (; o + 6 < end; o += 8) {
    const int s0 = csr[o], s1 = csr[o + 2], s2 = csr[o + 4], s3 = csr[o + 6];
    const ushort8 v0 = *reinterpret_cast<const ushort8*>(x + (size_t)s0 * D + fo);
    const ushort8 v1 = *reinterpret_cast<const ushort8*>(x + (size_t)s1 * D + fo);
    const ushort8 v2 = *reinterpret_cast<const ushort8*>(x + (size_t)s2 * D + fo);
    const ushort8 v3 = *reinterpret_cast<const ushort8*>(x + (size_t)s3 * D + fo);
#pragma unroll
    for (int j = 0; j < 8; ++j)
      acc[j] += (b2f(v0[j]) + b2f(v1[j])) + (b2f(v2[j]) + b2f(v3[j]));
  }
  for (; o < end; o += 2) {
    const ushort8 v = *reinterpret_cast<const ushort8*>(x + (size_t)csr[o] * D + fo);
#pragma unroll
    for (int j = 0; j < 8; ++j) acc[j] += b2f(v[j]);
  }

#pragma unroll
  for (int j = 0; j < 8; ++j) acc[j] += __shfl_xor(acc[j], 32, 64);

  if (half == 0) {
    ushort8 ov;
#pragma unroll
    for (int j = 0; j < 8; ++j) ov[j] = f2bf(acc[j]);
    *reinterpret_cast<ushort8*>(out + (size_t)node * D + fo) = ov;
  }
}

// ---------------------------------------------------------------------------
// C[r][c] = relu( sum_k A[r][k]*W[c][k] + bias[c] ), bf16 in / bf16 out.
// 4 waves, 64x64 tile, K=256 staged in LDS with XOR swizzle.
// ---------------------------------------------------------------------------
__global__ __launch_bounds__(256) void gemm_mfma_bf16(const ushort* __restrict__ A,
                                                      const ushort* __restrict__ W,
                                                      const float* __restrict__ bias,
                                                      ushort* __restrict__ C,
                                                      int M) {
  __shared__ __align__(16) ushort As[64 * 256];
  __shared__ __align__(16) ushort Ws[64 * 256];

  const int t = threadIdx.x;
  const int w = t >> 6, l = t & 63;
  const int row0 = blockIdx.x * 64;
  const int col0 = blockIdx.y * 64;

  {
    const float4 zero4 = {0.f, 0.f, 0.f, 0.f};
#pragma unroll
    for (int i = 0; i < 8; ++i) {
      const int chunk = t + i * 256;
      const int r  = chunk >> 5;
      const int kb = (chunk & 31) << 4;
      const int swz = kb ^ ((r & 7) << 4);
      const int grow = row0 + r;
      float4 av = zero4;
      if (grow < M)
        av = *reinterpret_cast<const float4*>(
            reinterpret_cast<const char*>(A) + (size_t)grow * 512 + kb);
      *reinterpret_cast<float4*>(reinterpret_cast<char*>(As) + r * 512 + swz) = av;
      const float4 wv = *reinterpret_cast<const float4*>(
          reinterpret_cast<const char*>(W) + (size_t)(col0 + r) * 512 + kb);
      *reinterpret_cast<float4*>(reinterpret_cast<char*>(Ws) + r * 512 + swz) = wv;
    }
  }
  __syncthreads();

  const int g  = l >> 4;
  const int fr = l & 15;

  frag_cd acc[4];
#pragma unroll
  for (int c = 0; c < 4; ++c) {
    acc[c][0] = 0.f; acc[c][1] = 0.f; acc[c][2] = 0.f; acc[c][3] = 0.f;
  }

  const int arow = w * 16 + fr;
  const char* Asb = reinterpret_cast<const char*>(As);
  const char* Wsb = reinterpret_cast<const char*>(Ws);
#pragma unroll
  for (int ks = 0; ks < 8; ++ks) {
    const int kb = ks * 64 + g * 16;
    const frag_ab af = *reinterpret_cast<const frag_ab*>(
        Asb + arow * 512 + (kb ^ ((arow & 7) << 4)));
#pragma unroll
    for (int c = 0; c < 4; ++c) {
      const int wrow = c * 16 + fr;
      const frag_ab bf = *reinterpret_cast<const frag_ab*>(
          Wsb + wrow * 512 + (kb ^ ((wrow & 7) << 4)));
      acc[c] = __builtin_amdgcn_mfma_f32_16x16x32_bf16(af, bf, acc[c], 0, 0, 0);
    }
  }
  __syncthreads();

  ushort* Ct = As;
#pragma unroll
  for (int c = 0; c < 4; ++c) {
    const int col = c * 16 + fr;
    const float bv = bias[col0 + col];
#pragma unroll
    for (int r = 0; r < 4; ++r) {
      const int rl = w * 16 + g * 4 + r;
      Ct[rl * 64 + col] = f2bf(fmaxf(acc[c][r] + bv, 0.f));
    }
  }
  __syncthreads();
#pragma unroll
  for (int i = 0; i < 2; ++i) {
    const int chunk = t + i * 256;
    const int r  = chunk >> 3;
    const int cb = (chunk & 7) << 4;
    const int grow = row0 + r;
    if (grow < M)
      *reinterpret_cast<float4*>(reinterpret_cast<char*>(C) + (size_t)grow * 512 + col0 * 2 + cb) =
          *reinterpret_cast<const float4*>(reinterpret_cast<const char*>(Ct) + r * 128 + cb);
  }
}

// ---------------------------------------------------------------------------
// Per-node head projection: proj[n] = (a0, a1, b0, b1)
// ---------------------------------------------------------------------------
__global__ __launch_bounds__(256) void proj_kernel(const ushort* __restrict__ h,
                                                   const float* __restrict__ W3,
                                                   float4* __restrict__ proj) {
  const int node = blockIdx.x * 4 + (threadIdx.x >> 6);
  const int lane = threadIdx.x & 63;
  if (node >= N_NODES) return;

  const ushort4 hv = *reinterpret_cast<const ushort4*>(h + (size_t)node * D + lane * 4);
  const float h0 = b2f(hv.x), h1 = b2f(hv.y), h2 = b2f(hv.z), h3 = b2f(hv.w);

  const float4 wa0 = *reinterpret_cast<const float4*>(W3 + lane * 4);
  const float4 wa1 = *reinterpret_cast<const float4*>(W3 + 512 + lane * 4);
  const float4 wb0 = *reinterpret_cast<const float4*>(W3 + 256 + lane * 4);
  const float4 wb1 = *reinterpret_cast<const float4*>(W3 + 768 + lane * 4);

  float a0 = h0 * wa0.x + h1 * wa0.y + h2 * wa0.z + h3 * wa0.w;
  float a1 = h0 * wa1.x + h1 * wa1.y + h2 * wa1.z + h3 * wa1.w;
  float b0 = h0 * wb0.x + h1 * wb0.y + h2 * wb0.z + h3 * wb0.w;
  float b1 = h0 * wb1.x + h1 * wb1.y + h2 * wb1.z + h3 * wb1.w;

#pragma unroll
  for (int off = 32; off > 0; off >>= 1) {
    a0 += __shfl_xor(a0, off, 64);
    a1 += __shfl_xor(a1, off, 64);
    b0 += __shfl_xor(b0, off, 64);
    b1 += __shfl_xor(b1, off, 64);
  }
  if (lane == 0) {
    float4 o; o.x = a0; o.y = a1; o.z = b0; o.w = b1;
    proj[node] = o;
  }
}

__global__ __launch_bounds__(256) void pair_lite(const float4* __restrict__ proj,
                                                 const int* __restrict__ idx,
                                                 const float* __restrict__ b3,
                                                 float* __restrict__ out) {
  const int p = blockIdx.x * blockDim.x + threadIdx.x;
  if (p >= N_PAIRS) return;
  const int2 ii = reinterpret_cast<const int2*>(idx)[p];
  const float4 pa = proj[ii.x];
  const float4 pb = proj[ii.y];
  float l0 = pa.x + pb.z + b3[0];
  float l1 = pa.y + pb.w + b3[1];
  const float m = fmaxf(l0, l1);
  const float lse = m + logf(expf(l0 - m) + expf(l1 - m));
  float2 o; o.x = l0 - lse; o.y = l1 - lse;
  reinterpret_cast<float2*>(out)[p] = o;
}

// ---------------------------------------------------------------------------
extern "C" void kernel_launch(void* const* d_in, const int* in_sizes, int n_in,
                              void* d_out, int out_size, void* d_ws, size_t ws_size,
                              hipStream_t stream) {
  const float* x   = (const float*)d_in[0];
  const int*   ei  = (const int*)d_in[1];
  const int*   idx = (const int*)d_in[2];
  const float* W1  = (const float*)d_in[3];
  const float* b1  = (const float*)d_in[4];
  const float* W2  = (const float*)d_in[5];
  const float* b2  = (const float*)d_in[6];
  const float* W3  = (const float*)d_in[7];
  const float* b3  = (const float*)d_in[8];
  float* out = (float*)d_out;

  char* ws = (char*)d_ws;
  ushort* xb    = (ushort*)(ws);                   // 51.2 MB
  ushort* aggb  = (ushort*)(ws + 51200000);        // 51.2 MB
  int2*   bucket= (int2*)(ws + 51200000);          // 25.6 MB, aliases aggb (build-time only)
  ushort* hb    = (ushort*)(ws + 102400000);       // 51.2 MB
  ushort* W1b   = (ushort*)(ws + 153600000);       // 128 KB
  ushort* W2b   = (ushort*)(ws + 153731072);       // 128 KB
  int* counts   = (int*)(ws + 153862144);          // SCANN ints
  int* cursor   = (int*)(ws + 154263552);
  int* pos      = (int*)(ws + 154664960);
  int* csr      = (int*)(ws + 155066368);          // 12.8 MB
  float4* proj  = (float4*)(ws + 167866368);       // 1.6 MB
  int* bsum     = (int*)(ws + 169466368);          // 98 ints
  int* bsum2    = (int*)(ws + 169466880);          // 98 ints
  int* rc       = (int*)(ws + 169467392);          // 8 ints

  const dim3 blk(256);
  const size_t feat = (size_t)N_NODES * D;
  constexpr int SCAN_BLOCKS = SCANN / 1024;        // 98
  const dim3 edgeGrid((N_EDGES + 255) / 256);
  const dim3 partGrid((N_EDGES + PART_SEG - 1) / PART_SEG);   // 782
  const dim3 flocGrid(NRANGE * FLB);                           // 1024
  const dim3 nodeGrid((N_NODES + 3) / 4);
  const dim3 gemmGrid((N_NODES + 63) / 64, D / 64);
  const dim3 pairGrid((N_PAIRS + 255) / 256);

  // ---- converts ----
  f32_to_bf16<<<dim3(4096), blk, 0, stream>>>((const float4*)x, (ushort4*)xb, (int)(feat / 4));
  conv_weights<<<dim3(128), blk, 0, stream>>>((const float4*)W1, (const float4*)W2,
                                              (ushort4*)W1b, (ushort4*)W2b);

  // ---- CSR build: hist -> hierarchical scan -> partition -> local fill ----
  zero_ints<<<dim3((SCANN + 255) / 256), blk, 0, stream>>>(counts, SCANN);
  hist_kernel<<<edgeGrid, blk, 0, stream>>>(ei, counts);
  scan_block_k<<<dim3(SCAN_BLOCKS), dim3(1024), 0, stream>>>(counts, cursor, bsum);
  scan_small<<<1, 1024, 0, stream>>>(bsum, bsum2, SCAN_BLOCKS);
  scan_add_k<<<dim3(SCAN_BLOCKS), dim3(1024), 0, stream>>>(cursor, pos, bsum2, rc);
  partition_kernel<<<partGrid, blk, 0, stream>>>(ei, rc, bucket);
  fill_local<<<flocGrid, blk, 0, stream>>>(bucket, cursor, pos, csr);

  // ---- layer 1 ----
  gather_agg_bf16<<<nodeGrid, blk, 0, stream>>>(xb, csr, cursor, counts, aggb);
  gemm_mfma_bf16<<<gemmGrid, blk, 0, stream>>>(aggb, W1b, b1, hb, N_NODES);

  // ---- layer 2 ----
  gather_agg_bf16<<<nodeGrid, blk, 0, stream>>>(hb, csr, cursor, counts, aggb);
  gemm_mfma_bf16<<<gemmGrid, blk, 0, stream>>>(aggb, W2b, b2, hb, N_NODES);

  // ---- pair head ----
  proj_kernel<<<nodeGrid, blk, 0, stream>>>(hb, W3, proj);
  pair_lite<<<pairGrid, blk, 0, stream>>>(proj, idx, b3, out);
}